// Round 7
// baseline (324.929 us; speedup 1.0000x reference)
//
#include <hip/hip_runtime.h>
#include <hip/hip_bf16.h>
#include <math.h>

#define BATCH 4
#define SEQ   2048
#define DM    1024
#define NH    16
#define DH    64
#define MROWS (BATCH * SEQ)   // 8192

typedef unsigned short ushort_t;
typedef unsigned int   uint_t;
typedef __attribute__((ext_vector_type(8))) short  short8;   // 8 bf16 (MFMA A/B frag)
typedef __attribute__((ext_vector_type(4))) float  float4v;  // MFMA C/D frag

#define QSCALE 0.1803368801111244f   // 0.125 * log2(e): logits in log2 domain

__device__ __forceinline__ ushort_t f2bf(float v) {  // RNE
    uint_t u = __float_as_uint(v);
    u += 0x7FFFu + ((u >> 16) & 1u);
    return (ushort_t)(u >> 16);
}
__device__ __forceinline__ float bf2f(ushort_t h) {
    return __uint_as_float(((uint_t)h) << 16);
}
__device__ __forceinline__ void gload_lds16(const ushort_t* g, ushort_t* lds) {
    __builtin_amdgcn_global_load_lds(
        (const __attribute__((address_space(1))) void*)g,
        (__attribute__((address_space(3))) void*)lds, 16, 0, 0);
}

// ---------------------------------------------------------------------------
// fp32 x -> bf16 (grid-strided: 2048 blocks x 4 float4/thread)
// ---------------------------------------------------------------------------
__global__ __launch_bounds__(256) void conv_x(
    const float* __restrict__ src, ushort_t* __restrict__ dst, int n4)
{
    int i = blockIdx.x * 256 + threadIdx.x;
#pragma unroll
    for (int k = 0; k < 4; k++, i += 524288) {
        float4 v = ((const float4*)src)[i];
        ((ushort4*)dst)[i] = make_ushort4(f2bf(v.x), f2bf(v.y), f2bf(v.z), f2bf(v.w));
    }
}

// ---------------------------------------------------------------------------
// All 4 weights, one launch (z selects): W[k][n] fp32 -> W^T[n][k] bf16.
// z=0..2 -> fused QKV buffer at n-offset z*1024; z=3 -> Wo hi + lo planes.
// ---------------------------------------------------------------------------
__global__ __launch_bounds__(256) void convT_w4(
    const float* __restrict__ W0, const float* __restrict__ W1,
    const float* __restrict__ W2, const float* __restrict__ W3,
    ushort_t* __restrict__ fused, ushort_t* __restrict__ woh,
    ushort_t* __restrict__ wol)
{
    __shared__ float sT[64][65];
    const int z = blockIdx.z;
    const float* W = (z == 0) ? W0 : (z == 1) ? W1 : (z == 2) ? W2 : W3;
    ushort_t* ht = (z < 3) ? fused + (size_t)z * 1024 * 1024 : woh;
    const int n0 = blockIdx.x * 64, k0 = blockIdx.y * 64;
    const int t = threadIdx.x;
#pragma unroll
    for (int i = 0; i < 16; i++) {
        int idx = t + i * 256, r = idx >> 6, c = idx & 63;
        sT[r][c] = W[(size_t)(k0 + r) * 1024 + n0 + c];
    }
    __syncthreads();
#pragma unroll
    for (int i = 0; i < 16; i++) {
        int idx = t + i * 256, r = idx >> 6, c = idx & 63;  // r = n, c = k
        float v = sT[c][r];
        ushort_t h = f2bf(v);
        ht[(size_t)(n0 + r) * 1024 + k0 + c] = h;
        if (z == 3) wol[(size_t)(n0 + r) * 1024 + k0 + c] = f2bf(v - bf2f(h));
    }
}

// ---------------------------------------------------------------------------
// Fused QKV GEMM (R9, measured best): tile 128x256, BK=64, 8 waves, 3-deep
// LDS buffer (144 KiB), counted vmcnt(6), grid 768 = 3 exact rounds.
// ---------------------------------------------------------------------------
#define BAR()   asm volatile("s_barrier" ::: "memory")
#define LGKM0() asm volatile("s_waitcnt lgkmcnt(0)" ::: "memory")
#define VMW6()  asm volatile("s_waitcnt vmcnt(6)" ::: "memory")

#define STAGE_A(BO, KT) do {                                                 \
    const ushort_t* _s = prowA + (size_t)((KT) & 15) * 64;                   \
    gload_lds16(_s,         &smem[(BO) + dstw]);                             \
    gload_lds16(_s + 65536, &smem[(BO) + 4096 + dstw]);                      \
  } while (0)

#define STAGE_B(BO, KT) do {                                                 \
    const ushort_t* _s = prowB + (size_t)((KT) & 15) * 64;                   \
    gload_lds16(_s,          &smem[(BO) + 8192  + dstw]);                    \
    gload_lds16(_s + 65536,  &smem[(BO) + 12288 + dstw]);                    \
    gload_lds16(_s + 131072, &smem[(BO) + 16384 + dstw]);                    \
    gload_lds16(_s + 196608, &smem[(BO) + 20480 + dstw]);                    \
  } while (0)

#define LOAD_AV(BO) do {                                                     \
    _Pragma("unroll")                                                        \
    for (int mf = 0; mf < 4; mf++) {                                         \
      av[mf][0] = *(const short8*)&smem[(BO) + aAm + mf * 1024 + aA0];       \
      av[mf][1] = *(const short8*)&smem[(BO) + aAm + mf * 1024 + aA1];       \
    }                                                                        \
  } while (0)

#define LOAD_BV(BO, NQ) do {                                                 \
    _Pragma("unroll")                                                        \
    for (int nf = 0; nf < 2; nf++) {                                         \
      bvf[nf][0] = *(const short8*)&smem[(BO) + 8192 + aBn + (NQ) * 2048 +   \
                                         nf * 1024 + aA0];                   \
      bvf[nf][1] = *(const short8*)&smem[(BO) + 8192 + aBn + (NQ) * 2048 +   \
                                         nf * 1024 + aA1];                   \
    }                                                                        \
  } while (0)

#define MFMA_H(NQ) do {                                                      \
    __builtin_amdgcn_s_setprio(1);                                           \
    _Pragma("unroll")                                                        \
    for (int kk = 0; kk < 2; kk++)                                           \
      _Pragma("unroll")                                                      \
      for (int nf = 0; nf < 2; nf++)                                         \
        _Pragma("unroll")                                                    \
        for (int mf = 0; mf < 4; mf++)                                       \
          acc[mf][(NQ) * 2 + nf] =                                           \
              __builtin_amdgcn_mfma_f32_16x16x32_bf16(                       \
                  av[mf][kk], bvf[nf][kk], acc[mf][(NQ) * 2 + nf], 0, 0, 0); \
    __builtin_amdgcn_s_setprio(0);                                           \
  } while (0)

__global__ __launch_bounds__(512, 2) void gemm_qkv(
    const ushort_t* __restrict__ A, const ushort_t* __restrict__ Bt,
    const float* __restrict__ bq, const float* __restrict__ bk,
    const float* __restrict__ bv, const int* __restrict__ mask,
    ushort_t* __restrict__ Qh, ushort_t* __restrict__ Kh,
    ushort_t* __restrict__ Vt)
{
    __shared__ __align__(16) ushort_t smem[73728];  // 144 KiB: 3 x 48 KiB bufs
    const int t = threadIdx.x, lane = t & 63, w = t >> 6;

    // XCD-aware swizzle (768 % 8 == 0 -> bijective)
    int bid = blockIdx.y * 12 + blockIdx.x;
    bid = (bid & 7) * 96 + (bid >> 3);
    const int n0 = (bid % 12) * 256, m0 = (bid / 12) * 128;

    const int wm = w >> 2, wn = w & 3;           // 2M x 4N wave grid
    const int lq = lane >> 4, lc = lane & 15;
    const int gl = (lane & 7) ^ ((lane >> 3) & 7);   // pre-swizzled source chunk
    const int sect = n0 >> 10;                   // 0=Q 1=K 2=V
    const float* bsel = (sect == 0) ? bq : (sect == 1) ? bk : bv;
    const float scl = (sect == 0) ? QSCALE : 1.0f;

    const ushort_t* prowA = A  + (size_t)(m0 + w * 8 + (lane >> 3)) * 1024 + gl * 8;
    const ushort_t* prowB = Bt + (size_t)(n0 + w * 8 + (lane >> 3)) * 1024 + gl * 8;
    const int dstw = w * 512;

    const int aA0 = lc * 64 + ((lq ^ (lc & 7)) * 8);
    const int aA1 = lc * 64 + (((4 + lq) ^ (lc & 7)) * 8);
    const int aAm = wm * 4096;
    const int aBn = wn * 4096;

    float4v acc[4][4];
#pragma unroll
    for (int i = 0; i < 4; i++)
#pragma unroll
        for (int j = 0; j < 4; j++) acc[i][j] = (float4v)(0.0f);

    short8 av[4][2], bvf[2][2];

    STAGE_A(0, 0); STAGE_B(0, 0); STAGE_A(24576, 1); STAGE_B(24576, 1);
    VMW6();
    BAR();

    int bc = 0, bs = 49152;
    for (int kt = 0; kt < 16; kt++) {
        LOAD_AV(bc); LOAD_BV(bc, 0); STAGE_A(bs, kt + 2);
        BAR(); LGKM0(); MFMA_H(0); BAR();
        LOAD_BV(bc, 1); STAGE_B(bs, kt + 2);
        BAR(); LGKM0(); MFMA_H(1); VMW6(); BAR();
        bc = (bc == 49152) ? 0 : bc + 24576;
        bs = (bs == 49152) ? 0 : bs + 24576;
    }

#pragma unroll
    for (int nf = 0; nf < 4; nf++) {
        const int nn = (n0 + wn * 64 + nf * 16 + lc) & 1023;
        const float bvv = bsel[nn];
        const int h = nn >> 6, d = nn & 63;
#pragma unroll
        for (int mf = 0; mf < 4; mf++) {
            const int mbase = m0 + wm * 64 + mf * 16 + lq * 4;
            const int b = mbase >> 11, s0 = mbase & 2047;
            int mk[4] = {1, 1, 1, 1};
            if (sect != 0) {
                const int4 m4 = *(const int4*)&mask[b * 2048 + s0];
                mk[0] = m4.x; mk[1] = m4.y; mk[2] = m4.z; mk[3] = m4.w;
            }
            if (sect == 2) {
                ushort_t hh[4];
#pragma unroll
                for (int r = 0; r < 4; r++)
                    hh[r] = mk[r] ? f2bf(acc[mf][nf][r] + bvv) : (ushort_t)0;
                *(ushort4*)&Vt[((size_t)(b * 16 + h) * 64 + d) * 2048 + s0] =
                    make_ushort4(hh[0], hh[1], hh[2], hh[3]);
            } else {
                ushort_t* dst = (sect == 0) ? Qh : Kh;
#pragma unroll
                for (int r = 0; r < 4; r++)
                    dst[((size_t)(b * 16 + h) * 2048 + s0 + r) * 64 + d] =
                        mk[r] ? f2bf((acc[mf][nf][r] + bvv) * scl) : (ushort_t)0;
            }
        }
    }
}

#undef STAGE_A
#undef STAGE_B
#undef LOAD_AV
#undef LOAD_BV
#undef MFMA_H

// ---------------------------------------------------------------------------
// split-bf16 GEMM (Wo) (R12): C = Ah*Bh + Al*Bh + Ah*Bl + bias, fp32 out.
// Tile 128x256(n), BK=32, 8 waves, grid 256 = one exact round, 3-deep buf,
// counted vmcnt(6), T2 chunk swizzle, setprio.
// ---------------------------------------------------------------------------
#define S3_STAGE3A(BO, KT) do {                                              \
    const size_t _k = (size_t)((KT) & 31) * 32;                              \
    gload_lds16(pAh + _k, &smem[(BO) + toff]);                               \
    gload_lds16(pAl + _k, &smem[(BO) + 4096 + toff]);                        \
    gload_lds16(pBh + _k, &smem[(BO) + 8192 + toff]);                        \
  } while (0)

#define S3_STAGE3B(BO, KT) do {                                              \
    const size_t _k = (size_t)((KT) & 31) * 32;                              \
    gload_lds16(pBh + 131072 + _k, &smem[(BO) + 12288 + toff]);              \
    gload_lds16(pBl + _k,          &smem[(BO) + 16384 + toff]);              \
    gload_lds16(pBl + 131072 + _k, &smem[(BO) + 20480 + toff]);              \
  } while (0)

#define S3_MFMA(NQ) do {                                                     \
    __builtin_amdgcn_s_setprio(1);                                           \
    _Pragma("unroll")                                                        \
    for (int nf = 0; nf < 2; nf++)                                           \
      _Pragma("unroll")                                                      \
      for (int mf = 0; mf < 4; mf++) {                                       \
        float4v* _a = &acc[mf][(NQ) * 2 + nf];                               \
        *_a = __builtin_amdgcn_mfma_f32_16x16x32_bf16(ah[mf], bh[nf], *_a, 0, 0, 0); \
        *_a = __builtin_amdgcn_mfma_f32_16x16x32_bf16(al[mf], bh[nf], *_a, 0, 0, 0); \
        *_a = __builtin_amdgcn_mfma_f32_16x16x32_bf16(ah[mf], bl[nf], *_a, 0, 0, 0); \
      }                                                                      \
    __builtin_amdgcn_s_setprio(0);                                           \
  } while (0)

__global__ __launch_bounds__(512, 2) void gemm_split3(
    const ushort_t* __restrict__ Ah, const ushort_t* __restrict__ Al,
    const ushort_t* __restrict__ Bh, const ushort_t* __restrict__ Bl,
    const float* __restrict__ bias, float* __restrict__ out)
{
    __shared__ __align__(16) ushort_t smem[73728];  // 144 KiB: 3 x 48 KiB
    const int t = threadIdx.x, lane = t & 63, w = t >> 6;

    int bid = blockIdx.y * 4 + blockIdx.x;
    bid = (bid & 7) * 32 + (bid >> 3);
    const int n0 = (bid % 4) * 256, m0 = (bid / 4) * 128;

    const int wm = w >> 2, wn = w & 3;
    const int lq = lane >> 4, lc = lane & 15;

    const int prow = t >> 2;
    const int pc = (t & 3) ^ (prow & 3);
    const size_t offA = (size_t)(m0 + prow) * 1024 + pc * 8;
    const size_t offB = (size_t)(n0 + prow) * 1024 + pc * 8;
    const ushort_t* pAh = Ah + offA;
    const ushort_t* pAl = Al + offA;
    const ushort_t* pBh = Bh + offB;
    const ushort_t* pBl = Bl + offB;
    const int toff = t * 8;

    const int aR = lc * 32 + ((lq ^ (lc & 3)) * 8);
    const int aAm = wm * 2048;
    const int aBn = wn * 2048;

    float4v acc[4][4];
#pragma unroll
    for (int i = 0; i < 4; i++)
#pragma unroll
        for (int j = 0; j < 4; j++) acc[i][j] = (float4v)(0.0f);

    short8 ah[4], al[4], bh[2], bl[2];

    S3_STAGE3A(0, 0);     S3_STAGE3B(0, 0);
    S3_STAGE3A(24576, 1); S3_STAGE3B(24576, 1);
    VMW6();
    BAR();

    int bc = 0, bs = 49152;
    for (int kt = 0; kt < 32; kt++) {
#pragma unroll
        for (int mf = 0; mf < 4; mf++) {
            ah[mf] = *(const short8*)&smem[bc + aAm + mf * 512 + aR];
            al[mf] = *(const short8*)&smem[bc + 4096 + aAm + mf * 512 + aR];
        }
#pragma unroll
        for (int nf = 0; nf < 2; nf++) {
            bh[nf] = *(const short8*)&smem[bc + 8192 + aBn + nf * 512 + aR];
            bl[nf] = *(const short8*)&smem[bc + 16384 + aBn + nf * 512 + aR];
        }
        S3_STAGE3A(bs, kt + 2);
        BAR(); LGKM0(); S3_MFMA(0); BAR();

#pragma unroll
        for (int nf = 0; nf < 2; nf++) {
            bh[nf] = *(const short8*)&smem[bc + 8192 + aBn + 1024 + nf * 512 + aR];
            bl[nf] = *(const short8*)&smem[bc + 16384 + aBn + 1024 + nf * 512 + aR];
        }
        S3_STAGE3B(bs, kt + 2);
        BAR(); LGKM0(); S3_MFMA(1); VMW6(); BAR();

        bc = (bc == 49152) ? 0 : bc + 24576;
        bs = (bs == 49152) ? 0 : bs + 24576;
    }

#pragma unroll
    for (int nf = 0; nf < 4; nf++) {
        const int n = n0 + wn * 64 + nf * 16 + lc;
        const float bvv = bias[n];
#pragma unroll
        for (int mf = 0; mf < 4; mf++)
#pragma unroll
            for (int r = 0; r < 4; r++) {
                const int m = m0 + wm * 64 + mf * 16 + lq * 4 + r;
                out[(size_t)m * 1024 + n] = acc[mf][nf][r] + bvv;
            }
    }
}

#undef S3_STAGE3A
#undef S3_STAGE3B
#undef S3_MFMA
#undef BAR
#undef LGKM0
#undef VMW6

// ---------------------------------------------------------------------------
// MFMA flash attention, exp2-domain no-max softmax.
// R14: LDS-pipe fix.  R10 profile arithmetic: ~320 ds_read_b128/CU-iter x
// 12cyc + ~1000cyc conflicted P-stores ~= 76% LDS-busy -> LDS-bound, not
// MFMA-bound.  Two levers:
// (1) 4 waves x 64 q-rows (QBLK=256) at TWO blocks/CU (LDS exactly 64 KiB):
//     per-wave LDS reads 24/iter for 72 MFMA (vs R10: 20 for 36) -- halves
//     read instrs per MFMA; independent co-resident blocks fill each
//     other's barrier/drain stalls (R13's 1-blk lockstep was the regression).
//     Grid 8 x 64 = 512 = ONE exact round at 2/CU.
// (2) lcs bank swizzle: lcs = (lc&7) ^ ((lc>>3)<<2) replaces lc&7 in EVERY
//     LDS slot XOR (reads aK/aPw/aq + all staging source pre-permutes, which
//     gain the matching ((row>>3)&1)<<2 bit).  Kills the lanes-(lc,lc+8)
//     same-bank collision: P-stores (4.19M conflict cycles) become
//     conflict-free; b128 reads drop to the free 2-way minimum.
// Sync skeleton = R10 (proven): stage tile kt+1 at TOP of iter kt into the
// other dbuf half, ONE vmcnt(0)+s_barrier at bottom.  l via ones-column
// MFMA (R10); mask folded into K/V upstream; Q pre-scaled; exact masked
// count nmaskf in V-buf1 scratch guarded by the lgkmcnt+barrier pair.
// smem (ushort): sQ/sP wave w at w*4096 (32 KiB) | K dbuf 16384+buf*4096 |
// V dbuf 24576+buf*4096 -> 65536 B; 2 blocks/CU = 128 KiB <= 160.
// ---------------------------------------------------------------------------
#define FBAR()   asm volatile("s_barrier" ::: "memory")
#define FLGKM0() asm volatile("s_waitcnt lgkmcnt(0)" ::: "memory")
#define FVMW0()  asm volatile("s_waitcnt vmcnt(0)" ::: "memory")

__global__ __launch_bounds__(256, 2) void flash_mfma(
    const ushort_t* __restrict__ Q, const ushort_t* __restrict__ K,
    const ushort_t* __restrict__ Vt, const int* __restrict__ mask,
    ushort_t* __restrict__ Oh, ushort_t* __restrict__ Ol)
{
    __shared__ __align__(16) ushort_t smem[32768];   // 64 KiB
    const int t = threadIdx.x, lane = t & 63, w = t >> 6;
    const int q0 = blockIdx.x * 256;
    const int bh = blockIdx.y, b = bh >> 4, h = bh & 15;
    const int lq = lane >> 4, lc = lane & 15;
    const int lcs = (lc & 7) ^ ((lc >> 3) << 2);
    const int wq = w * 64;

    // B-frag for the l-MFMA: column 0 = 1.0 (bf16), all other columns 0
    const short8 onesf = (short8)(lc == 0 ? (short)0x3F80 : (short)0);

    // ---- mask loads (2048 ints / 256 threads = 2 int4 each)
    const int4 ma0 = ((const int4*)(mask + b * SEQ))[t];
    const int4 ma1 = ((const int4*)(mask + b * SEQ))[t + 256];

    // ---- Q staging: wave w's 64 rows -> smem[w*4096]; row-bit-3 = j&1
    const int trow = lane >> 3;
    const int gl0 = (lane & 7) ^ trow;
    const ushort_t* qbase = Q + ((size_t)bh * SEQ + q0 + wq + trow) * 64;
    const ushort_t* qE = qbase + gl0 * 8;                // rows j*8, j even
    const ushort_t* qO = qbase + 512 + (gl0 ^ 4) * 8;    // rows j*8, j odd
#pragma unroll
    for (int j = 0; j < 4; j++) {
        gload_lds16(qE + j * 1024, &smem[w * 4096 + (2 * j) * 512 + lane * 8]);
        gload_lds16(qO + j * 1024, &smem[w * 4096 + (2 * j + 1) * 512 + lane * 8]);
    }

    // ---- K/V staging bases: thread t covers row (t>>3) (+32 for half 1)
    const int sgl = (t & 7) ^ ((t >> 3) & 7) ^ (((t >> 6) & 1) << 2);
    const ushort_t* kb0 = K  + ((size_t)bh * SEQ + (t >> 3)) * 64 + sgl * 8;
    const ushort_t* vb0 = Vt + ((size_t)bh * 64 + (t >> 3)) * SEQ + sgl * 8;

    // tile 0 -> buf0 (4 instrs/thread)
    gload_lds16(kb0,             &smem[16384 + t * 8]);
    gload_lds16(kb0 + 2048,      &smem[16384 + 2048 + t * 8]);
    gload_lds16(vb0,             &smem[24576 + t * 8]);
    gload_lds16(vb0 + 32 * SEQ,  &smem[24576 + 2048 + t * 8]);

    // ---- masked-key count; scratch = V buf1 region (staged first at iter 0)
    int cnt = (ma0.x == 0) + (ma0.y == 0) + (ma0.z == 0) + (ma0.w == 0) +
              (ma1.x == 0) + (ma1.y == 0) + (ma1.z == 0) + (ma1.w == 0);
#pragma unroll
    for (int off = 1; off < 64; off <<= 1) cnt += __shfl_xor(cnt, off);
    if (lane == 0) ((float*)&smem[28672])[w] = (float)cnt;

    __syncthreads();   // drains vmcnt+lgkm: Q, K0, V0 landed; cnt visible

    const float* cs = (const float*)&smem[28672];
    const float nmaskf = cs[0] + cs[1] + cs[2] + cs[3];

    // ---- per-lane slot offsets (ushort units), lcs-swizzled
    int aKo[2], aPw[4];
#pragma unroll
    for (int kk = 0; kk < 2; kk++)
        aKo[kk] = lc * 64 + (((kk * 4 + lq) ^ lcs) * 8);
#pragma unroll
    for (int kt4 = 0; kt4 < 4; kt4++)
        aPw[kt4] = lc * 64 + (((kt4 * 2 + (lq >> 1)) ^ lcs) * 8) + (lq & 1) * 4;

    // ---- Q frags -> regs (sQ region becomes sP)
    short8 aq[4][2];
#pragma unroll
    for (int mt = 0; mt < 4; mt++)
#pragma unroll
        for (int kk = 0; kk < 2; kk++)
            aq[mt][kk] = *(const short8*)&smem[w * 4096 + mt * 1024 + aKo[kk]];

    FLGKM0();   // own cnt/aq reads returned
    FBAR();     // ...before any wave issues iter-0 staging (into V buf1 etc.)

    float4v O[4][4];
    float4v lacc[4];
#pragma unroll
    for (int mt = 0; mt < 4; mt++) {
#pragma unroll
        for (int nt = 0; nt < 4; nt++) O[mt][nt] = (float4v)(0.0f);
        lacc[mt] = (float4v)(0.0f);
    }

    for (int kt = 0; kt < 32; kt++) {
        const int cur = (kt & 1) * 4096;
        const int nxt = cur ^ 4096;

        // ---- stage tile kt+1 FIRST (hides under this iter's 72 MFMA)
        if (kt < 31) {
            const ushort_t* kn = kb0 + (size_t)(kt + 1) * 4096;
            const ushort_t* vn = vb0 + (size_t)(kt + 1) * 64;
            gload_lds16(kn,            &smem[16384 + nxt + t * 8]);
            gload_lds16(kn + 2048,     &smem[16384 + nxt + 2048 + t * 8]);
            gload_lds16(vn,            &smem[24576 + nxt + t * 8]);
            gload_lds16(vn + 32 * SEQ, &smem[24576 + nxt + 2048 + t * 8]);
        }

        const int kb = 16384 + cur, vb = 24576 + cur, pb = w * 4096;

        // ---- S^T = K Q^T per kt4; p = exp2(s); pack + store to sP
#pragma unroll
        for (int kt4 = 0; kt4 < 4; kt4++) {
            float4v sc[4];
#pragma unroll
            for (int mt = 0; mt < 4; mt++) sc[mt] = (float4v)(0.0f);
#pragma unroll
            for (int kk = 0; kk < 2; kk++) {
                const short8 ak = *(const short8*)&smem[kb + kt4 * 1024 + aKo[kk]];
#pragma unroll
                for (int mt = 0; mt < 4; mt++)
                    sc[mt] = __builtin_amdgcn_mfma_f32_16x16x32_bf16(ak, aq[mt][kk], sc[mt], 0, 0, 0);
            }
#pragma unroll
            for (int mt = 0; mt < 4; mt++) {
                const float p0 = __builtin_amdgcn_exp2f(sc[mt][0]);
                const float p1 = __builtin_amdgcn_exp2f(sc[mt][1]);
                const float p2 = __builtin_amdgcn_exp2f(sc[mt][2]);
                const float p3 = __builtin_amdgcn_exp2f(sc[mt][3]);
                __hip_bfloat162 pk01 = __float22bfloat162_rn(make_float2(p0, p1));
                __hip_bfloat162 pk23 = __float22bfloat162_rn(make_float2(p2, p3));
                *(uint2*)&smem[pb + mt * 1024 + aPw[kt4]] =
                    make_uint2(*(const uint_t*)&pk01, *(const uint_t*)&pk23);
            }
        }

        // ---- O += P @ V ; l += P @ ones-col (wave-private P; in-order LDS)
#pragma unroll
        for (int kk = 0; kk < 2; kk++) {
            short8 ap[4];
#pragma unroll
            for (int mt = 0; mt < 4; mt++)
                ap[mt] = *(const short8*)&smem[pb + mt * 1024 + aKo[kk]];
            __builtin_amdgcn_s_setprio(1);
#pragma unroll
            for (int mt = 0; mt < 4; mt++)
                lacc[mt] = __builtin_amdgcn_mfma_f32_16x16x32_bf16(ap[mt], onesf, lacc[mt], 0, 0, 0);
#pragma unroll
            for (int nt = 0; nt < 4; nt++) {
                const short8 bv = *(const short8*)&smem[vb + nt * 1024 + aKo[kk]];
#pragma unroll
                for (int mt = 0; mt < 4; mt++)
                    O[mt][nt] = __builtin_amdgcn_mfma_f32_16x16x32_bf16(ap[mt], bv, O[mt][nt], 0, 0, 0);
            }
            __builtin_amdgcn_s_setprio(0);
        }

        // ---- own staging landed + all waves done reading [cur]
        FVMW0();
        FBAR();
    }

    // ---- epilogue: l in col 0 of C-layout; subtract masked count; normalize
#pragma unroll
    for (int mt = 0; mt < 4; mt++) {
#pragma unroll
        for (int r = 0; r < 4; r++) {
            const float lsum = __shfl(lacc[mt][r], lane & 48) - nmaskf;
            const float inv = 1.0f / lsum;
            const int srow = q0 + wq + mt * 16 + lq * 4 + r;
#pragma unroll
            for (int nt = 0; nt < 4; nt++) {
                const float v = O[mt][nt][r] * inv;
                const ushort_t hh = f2bf(v);
                const size_t idx = ((size_t)(b * SEQ + srow)) * 1024 + h * 64 + nt * 16 + lc;
                Oh[idx] = hh;
                Ol[idx] = f2bf(v - bf2f(hh));
            }
        }
    }
}

#undef FBAR
#undef FLGKM0
#undef FVMW0

extern "C" void kernel_launch(void* const* d_in, const int* in_sizes, int n_in,
                              void* d_out, int out_size, void* d_ws, size_t ws_size,
                              hipStream_t stream) {
    const float* x    = (const float*)d_in[0];
    const int*   mask = (const int*)d_in[1];
    const float* Wq   = (const float*)d_in[2];
    const float* bq   = (const float*)d_in[3];
    const float* Wk   = (const float*)d_in[4];
    const float* bk   = (const float*)d_in[5];
    const float* Wv   = (const float*)d_in[6];
    const float* bv   = (const float*)d_in[7];
    const float* Wo   = (const float*)d_in[8];
    const float* bo   = (const float*)d_in[9];
    float* out = (float*)d_out;

    ushort_t* p = (ushort_t*)d_ws;
    const size_t PLANE  = (size_t)MROWS * DM;
    const size_t WPLANE = (size_t)DM * DM;
    ushort_t* xh  = p;  p += PLANE;
    ushort_t* wf  = p;  p += 3 * WPLANE;   // fused [Wq|Wk|Wv]^T
    ushort_t* woh = p;  p += WPLANE;
    ushort_t* wol = p;  p += WPLANE;
    ushort_t* Qh  = p;  p += PLANE;
    ushort_t* Kh  = p;  p += PLANE;
    ushort_t* Vth = p;  p += PLANE;
    ushort_t* Ath = p;  p += PLANE;
    ushort_t* Atl = p;  p += PLANE;

    dim3 blk(256);
    hipLaunchKernelGGL(conv_x, dim3(2048), blk, 0, stream, x, xh, 2097152);
    hipLaunchKernelGGL(convT_w4, dim3(16, 16, 4), blk, 0, stream,
                       Wq, Wk, Wv, Wo, wf, woh, wol);
    hipLaunchKernelGGL(gemm_qkv, dim3(12, 64), dim3(512), 0, stream,
                       xh, wf, bq, bk, bv, mask, Qh, Kh, Vth);
    hipLaunchKernelGGL(flash_mfma, dim3(8, 64), blk, 0, stream,
                       Qh, Kh, Vth, mask, Ath, Atl);
    hipLaunchKernelGGL(gemm_split3, dim3(4, 64), dim3(512), 0, stream,
                       Ath, Atl, woh, wol, bo, out);
}

// Round 8
// 309.164 us; speedup vs baseline: 1.0510x; 1.0510x over previous
//
#include <hip/hip_runtime.h>
#include <hip/hip_bf16.h>
#include <math.h>

#define BATCH 4
#define SEQ   2048
#define DM    1024
#define NH    16
#define DH    64
#define MROWS (BATCH * SEQ)   // 8192

typedef unsigned short ushort_t;
typedef unsigned int   uint_t;
typedef __attribute__((ext_vector_type(8))) short  short8;   // 8 bf16 (MFMA A/B frag)
typedef __attribute__((ext_vector_type(4))) float  float4v;  // MFMA C/D frag

#define QSCALE 0.1803368801111244f   // 0.125 * log2(e): logits in log2 domain

__device__ __forceinline__ ushort_t f2bf(float v) {  // RNE
    uint_t u = __float_as_uint(v);
    u += 0x7FFFu + ((u >> 16) & 1u);
    return (ushort_t)(u >> 16);
}
__device__ __forceinline__ float bf2f(ushort_t h) {
    return __uint_as_float(((uint_t)h) << 16);
}
__device__ __forceinline__ void gload_lds16(const ushort_t* g, ushort_t* lds) {
    __builtin_amdgcn_global_load_lds(
        (const __attribute__((address_space(1))) void*)g,
        (__attribute__((address_space(3))) void*)lds, 16, 0, 0);
}

// ---------------------------------------------------------------------------
// R15 prep: conv_x + convT_w4 merged into ONE launch (independent DAG roots;
// saves one launch gap).  Blocks 0..2047: x fp32->bf16 (grid-strided float4).
// Blocks 2048..3071: weight transpose, id decodes the old dim3(16,16,4).
// ---------------------------------------------------------------------------
__global__ __launch_bounds__(256) void prep(
    const float* __restrict__ x, ushort_t* __restrict__ xh,
    const float* __restrict__ W0, const float* __restrict__ W1,
    const float* __restrict__ W2, const float* __restrict__ W3,
    ushort_t* __restrict__ fused, ushort_t* __restrict__ woh,
    ushort_t* __restrict__ wol)
{
    __shared__ float sT[64][65];
    const int t = threadIdx.x;

    if (blockIdx.x < 2048) {
        int i = blockIdx.x * 256 + t;
#pragma unroll
        for (int k = 0; k < 4; k++, i += 524288) {
            float4 v = ((const float4*)x)[i];
            ((ushort4*)xh)[i] = make_ushort4(f2bf(v.x), f2bf(v.y), f2bf(v.z), f2bf(v.w));
        }
        return;
    }

    const int id = blockIdx.x - 2048;
    const int z = id >> 8;
    const float* W = (z == 0) ? W0 : (z == 1) ? W1 : (z == 2) ? W2 : W3;
    ushort_t* ht = (z < 3) ? fused + (size_t)z * 1024 * 1024 : woh;
    const int n0 = (id & 15) * 64, k0 = ((id >> 4) & 15) * 64;
#pragma unroll
    for (int i = 0; i < 16; i++) {
        int idx = t + i * 256, r = idx >> 6, c = idx & 63;
        sT[r][c] = W[(size_t)(k0 + r) * 1024 + n0 + c];
    }
    __syncthreads();
#pragma unroll
    for (int i = 0; i < 16; i++) {
        int idx = t + i * 256, r = idx >> 6, c = idx & 63;  // r = n, c = k
        float v = sT[c][r];
        ushort_t h = f2bf(v);
        ht[(size_t)(n0 + r) * 1024 + k0 + c] = h;
        if (z == 3) wol[(size_t)(n0 + r) * 1024 + k0 + c] = f2bf(v - bf2f(h));
    }
}

// ---------------------------------------------------------------------------
// Fused QKV GEMM (R9, measured best 88.0 us): C = x @ [Wq|Wk|Wv]^T + bias.
// Tile 128x256, BK=64, 512 thr / 8 waves (2M x 4N), per-wave 64x64.
// Grid 64x12 = 768 = 3 exact rounds of 256 CUs at 1 block/CU.
// 2 phases per K-tile, 3-deep LDS buffer (144 KiB), counted vmcnt(6).
// ---------------------------------------------------------------------------
#define BAR()   asm volatile("s_barrier" ::: "memory")
#define LGKM0() asm volatile("s_waitcnt lgkmcnt(0)" ::: "memory")
#define VMW6()  asm volatile("s_waitcnt vmcnt(6)" ::: "memory")

#define STAGE_A(BO, KT) do {                                                 \
    const ushort_t* _s = prowA + (size_t)((KT) & 15) * 64;                   \
    gload_lds16(_s,         &smem[(BO) + dstw]);                             \
    gload_lds16(_s + 65536, &smem[(BO) + 4096 + dstw]);                      \
  } while (0)

#define STAGE_B(BO, KT) do {                                                 \
    const ushort_t* _s = prowB + (size_t)((KT) & 15) * 64;                   \
    gload_lds16(_s,          &smem[(BO) + 8192  + dstw]);                    \
    gload_lds16(_s + 65536,  &smem[(BO) + 12288 + dstw]);                    \
    gload_lds16(_s + 131072, &smem[(BO) + 16384 + dstw]);                    \
    gload_lds16(_s + 196608, &smem[(BO) + 20480 + dstw]);                    \
  } while (0)

#define LOAD_AV(BO) do {                                                     \
    _Pragma("unroll")                                                        \
    for (int mf = 0; mf < 4; mf++) {                                         \
      av[mf][0] = *(const short8*)&smem[(BO) + aAm + mf * 1024 + aA0];       \
      av[mf][1] = *(const short8*)&smem[(BO) + aAm + mf * 1024 + aA1];       \
    }                                                                        \
  } while (0)

#define LOAD_BV(BO, NQ) do {                                                 \
    _Pragma("unroll")                                                        \
    for (int nf = 0; nf < 2; nf++) {                                         \
      bvf[nf][0] = *(const short8*)&smem[(BO) + 8192 + aBn + (NQ) * 2048 +   \
                                         nf * 1024 + aA0];                   \
      bvf[nf][1] = *(const short8*)&smem[(BO) + 8192 + aBn + (NQ) * 2048 +   \
                                         nf * 1024 + aA1];                   \
    }                                                                        \
  } while (0)

#define MFMA_H(NQ) do {                                                      \
    __builtin_amdgcn_s_setprio(1);                                           \
    _Pragma("unroll")                                                        \
    for (int kk = 0; kk < 2; kk++)                                           \
      _Pragma("unroll")                                                      \
      for (int nf = 0; nf < 2; nf++)                                         \
        _Pragma("unroll")                                                    \
        for (int mf = 0; mf < 4; mf++)                                       \
          acc[mf][(NQ) * 2 + nf] =                                           \
              __builtin_amdgcn_mfma_f32_16x16x32_bf16(                       \
                  av[mf][kk], bvf[nf][kk], acc[mf][(NQ) * 2 + nf], 0, 0, 0); \
    __builtin_amdgcn_s_setprio(0);                                           \
  } while (0)

__global__ __launch_bounds__(512, 2) void gemm_qkv(
    const ushort_t* __restrict__ A, const ushort_t* __restrict__ Bt,
    const float* __restrict__ bq, const float* __restrict__ bk,
    const float* __restrict__ bv, const int* __restrict__ mask,
    ushort_t* __restrict__ Qh, ushort_t* __restrict__ Kh,
    ushort_t* __restrict__ Vt)
{
    __shared__ __align__(16) ushort_t smem[73728];  // 144 KiB: 3 x 48 KiB bufs
    const int t = threadIdx.x, lane = t & 63, w = t >> 6;

    // XCD-aware swizzle (768 % 8 == 0 -> bijective)
    int bid = blockIdx.y * 12 + blockIdx.x;
    bid = (bid & 7) * 96 + (bid >> 3);
    const int n0 = (bid % 12) * 256, m0 = (bid / 12) * 128;

    const int wm = w >> 2, wn = w & 3;           // 2M x 4N wave grid
    const int lq = lane >> 4, lc = lane & 15;
    const int gl = (lane & 7) ^ ((lane >> 3) & 7);   // pre-swizzled source chunk
    const int sect = n0 >> 10;                   // 0=Q 1=K 2=V
    const float* bsel = (sect == 0) ? bq : (sect == 1) ? bk : bv;
    const float scl = (sect == 0) ? QSCALE : 1.0f;

    const ushort_t* prowA = A  + (size_t)(m0 + w * 8 + (lane >> 3)) * 1024 + gl * 8;
    const ushort_t* prowB = Bt + (size_t)(n0 + w * 8 + (lane >> 3)) * 1024 + gl * 8;
    const int dstw = w * 512;

    const int aA0 = lc * 64 + ((lq ^ (lc & 7)) * 8);
    const int aA1 = lc * 64 + (((4 + lq) ^ (lc & 7)) * 8);
    const int aAm = wm * 4096;
    const int aBn = wn * 4096;

    float4v acc[4][4];
#pragma unroll
    for (int i = 0; i < 4; i++)
#pragma unroll
        for (int j = 0; j < 4; j++) acc[i][j] = (float4v)(0.0f);

    short8 av[4][2], bvf[2][2];

    STAGE_A(0, 0); STAGE_B(0, 0); STAGE_A(24576, 1); STAGE_B(24576, 1);
    VMW6();
    BAR();

    int bc = 0, bs = 49152;
    for (int kt = 0; kt < 16; kt++) {
        LOAD_AV(bc); LOAD_BV(bc, 0); STAGE_A(bs, kt + 2);
        BAR(); LGKM0(); MFMA_H(0); BAR();
        LOAD_BV(bc, 1); STAGE_B(bs, kt + 2);
        BAR(); LGKM0(); MFMA_H(1); VMW6(); BAR();
        bc = (bc == 49152) ? 0 : bc + 24576;
        bs = (bs == 49152) ? 0 : bs + 24576;
    }

#pragma unroll
    for (int nf = 0; nf < 4; nf++) {
        const int nn = (n0 + wn * 64 + nf * 16 + lc) & 1023;
        const float bvv = bsel[nn];
        const int h = nn >> 6, d = nn & 63;
#pragma unroll
        for (int mf = 0; mf < 4; mf++) {
            const int mbase = m0 + wm * 64 + mf * 16 + lq * 4;
            const int b = mbase >> 11, s0 = mbase & 2047;
            int mk[4] = {1, 1, 1, 1};
            if (sect != 0) {
                const int4 m4 = *(const int4*)&mask[b * 2048 + s0];
                mk[0] = m4.x; mk[1] = m4.y; mk[2] = m4.z; mk[3] = m4.w;
            }
            if (sect == 2) {
                ushort_t hh[4];
#pragma unroll
                for (int r = 0; r < 4; r++)
                    hh[r] = mk[r] ? f2bf(acc[mf][nf][r] + bvv) : (ushort_t)0;
                *(ushort4*)&Vt[((size_t)(b * 16 + h) * 64 + d) * 2048 + s0] =
                    make_ushort4(hh[0], hh[1], hh[2], hh[3]);
            } else {
                ushort_t* dst = (sect == 0) ? Qh : Kh;
#pragma unroll
                for (int r = 0; r < 4; r++)
                    dst[((size_t)(b * 16 + h) * 2048 + s0 + r) * 64 + d] =
                        mk[r] ? f2bf((acc[mf][nf][r] + bvv) * scl) : (ushort_t)0;
            }
        }
    }
}

#undef STAGE_A
#undef STAGE_B
#undef LOAD_AV
#undef LOAD_BV
#undef MFMA_H

// ---------------------------------------------------------------------------
// split-bf16 GEMM (Wo) (R12): C = Ah*Bh + Al*Bh + Ah*Bl + bias, fp32 out.
// Tile 128x256(n), BK=32, 8 waves, grid 256 = one exact round, 3-deep buf,
// counted vmcnt(6), T2 chunk swizzle, setprio.
// ---------------------------------------------------------------------------
#define S3_STAGE3A(BO, KT) do {                                              \
    const size_t _k = (size_t)((KT) & 31) * 32;                              \
    gload_lds16(pAh + _k, &smem[(BO) + toff]);                               \
    gload_lds16(pAl + _k, &smem[(BO) + 4096 + toff]);                        \
    gload_lds16(pBh + _k, &smem[(BO) + 8192 + toff]);                        \
  } while (0)

#define S3_STAGE3B(BO, KT) do {                                              \
    const size_t _k = (size_t)((KT) & 31) * 32;                              \
    gload_lds16(pBh + 131072 + _k, &smem[(BO) + 12288 + toff]);              \
    gload_lds16(pBl + _k,          &smem[(BO) + 16384 + toff]);              \
    gload_lds16(pBl + 131072 + _k, &smem[(BO) + 20480 + toff]);              \
  } while (0)

#define S3_MFMA(NQ) do {                                                     \
    __builtin_amdgcn_s_setprio(1);                                           \
    _Pragma("unroll")                                                        \
    for (int nf = 0; nf < 2; nf++)                                           \
      _Pragma("unroll")                                                      \
      for (int mf = 0; mf < 4; mf++) {                                       \
        float4v* _a = &acc[mf][(NQ) * 2 + nf];                               \
        *_a = __builtin_amdgcn_mfma_f32_16x16x32_bf16(ah[mf], bh[nf], *_a, 0, 0, 0); \
        *_a = __builtin_amdgcn_mfma_f32_16x16x32_bf16(al[mf], bh[nf], *_a, 0, 0, 0); \
        *_a = __builtin_amdgcn_mfma_f32_16x16x32_bf16(ah[mf], bl[nf], *_a, 0, 0, 0); \
      }                                                                      \
    __builtin_amdgcn_s_setprio(0);                                           \
  } while (0)

__global__ __launch_bounds__(512, 2) void gemm_split3(
    const ushort_t* __restrict__ Ah, const ushort_t* __restrict__ Al,
    const ushort_t* __restrict__ Bh, const ushort_t* __restrict__ Bl,
    const float* __restrict__ bias, float* __restrict__ out)
{
    __shared__ __align__(16) ushort_t smem[73728];  // 144 KiB: 3 x 48 KiB
    const int t = threadIdx.x, lane = t & 63, w = t >> 6;

    int bid = blockIdx.y * 4 + blockIdx.x;
    bid = (bid & 7) * 32 + (bid >> 3);
    const int n0 = (bid % 4) * 256, m0 = (bid / 4) * 128;

    const int wm = w >> 2, wn = w & 3;
    const int lq = lane >> 4, lc = lane & 15;

    const int prow = t >> 2;
    const int pc = (t & 3) ^ (prow & 3);
    const size_t offA = (size_t)(m0 + prow) * 1024 + pc * 8;
    const size_t offB = (size_t)(n0 + prow) * 1024 + pc * 8;
    const ushort_t* pAh = Ah + offA;
    const ushort_t* pAl = Al + offA;
    const ushort_t* pBh = Bh + offB;
    const ushort_t* pBl = Bl + offB;
    const int toff = t * 8;

    const int aR = lc * 32 + ((lq ^ (lc & 3)) * 8);
    const int aAm = wm * 2048;
    const int aBn = wn * 2048;

    float4v acc[4][4];
#pragma unroll
    for (int i = 0; i < 4; i++)
#pragma unroll
        for (int j = 0; j < 4; j++) acc[i][j] = (float4v)(0.0f);

    short8 ah[4], al[4], bh[2], bl[2];

    S3_STAGE3A(0, 0);     S3_STAGE3B(0, 0);
    S3_STAGE3A(24576, 1); S3_STAGE3B(24576, 1);
    VMW6();
    BAR();

    int bc = 0, bs = 49152;
    for (int kt = 0; kt < 32; kt++) {
#pragma unroll
        for (int mf = 0; mf < 4; mf++) {
            ah[mf] = *(const short8*)&smem[bc + aAm + mf * 512 + aR];
            al[mf] = *(const short8*)&smem[bc + 4096 + aAm + mf * 512 + aR];
        }
#pragma unroll
        for (int nf = 0; nf < 2; nf++) {
            bh[nf] = *(const short8*)&smem[bc + 8192 + aBn + nf * 512 + aR];
            bl[nf] = *(const short8*)&smem[bc + 16384 + aBn + nf * 512 + aR];
        }
        S3_STAGE3A(bs, kt + 2);
        BAR(); LGKM0(); S3_MFMA(0); BAR();

#pragma unroll
        for (int nf = 0; nf < 2; nf++) {
            bh[nf] = *(const short8*)&smem[bc + 8192 + aBn + 1024 + nf * 512 + aR];
            bl[nf] = *(const short8*)&smem[bc + 16384 + aBn + 1024 + nf * 512 + aR];
        }
        S3_STAGE3B(bs, kt + 2);
        BAR(); LGKM0(); S3_MFMA(1); VMW6(); BAR();

        bc = (bc == 49152) ? 0 : bc + 24576;
        bs = (bs == 49152) ? 0 : bs + 24576;
    }

#pragma unroll
    for (int nf = 0; nf < 4; nf++) {
        const int n = n0 + wn * 64 + nf * 16 + lc;
        const float bvv = bias[n];
#pragma unroll
        for (int mf = 0; mf < 4; mf++)
#pragma unroll
            for (int r = 0; r < 4; r++) {
                const int m = m0 + wm * 64 + mf * 16 + lq * 4 + r;
                out[(size_t)m * 1024 + n] = acc[mf][nf][r] + bvv;
            }
    }
}

#undef S3_STAGE3A
#undef S3_STAGE3B
#undef S3_MFMA
#undef BAR
#undef LGKM0
#undef VMW6

// ---------------------------------------------------------------------------
// MFMA flash attention (R10, measured best <=88 us), exp2-domain no-max
// softmax.  QBLK=256, 512 thr / 8 waves (32 q-rows each); 512 blocks at
// 2 blocks/CU (one exact round of the doubled capacity).  K/V
// double-buffered; tile kt+1's staging issued at TOP of iter kt; ONE
// barrier per iter.
// R15 delta (ONLY change vs R10): XCD-aware block remap -- hw-linear id i:
// bh = (i&7) + 8*((i>>3)&7), q0 = (i>>6)*256.  Each XCD owns 8 heads x all
// 8 q-blocks -> K/V working set 4 MB/XCD (L2-resident); R13 measured this
// grouping cuts flash FETCH 143 -> ~25-40 MB.  Pure index bijection.
// ---------------------------------------------------------------------------
__global__ __launch_bounds__(512, 4) void flash_mfma(
    const ushort_t* __restrict__ Q, const ushort_t* __restrict__ K,
    const ushort_t* __restrict__ Vt, const int* __restrict__ mask,
    ushort_t* __restrict__ Oh, ushort_t* __restrict__ Ol)
{
    __shared__ __align__(16) ushort_t smem[32768];   // 64 KiB
    const int t = threadIdx.x, lane = t & 63, w = t >> 6;

    const int i = blockIdx.x + blockIdx.y * 8;       // hw-linear (x fastest)
    const int bh = (i & 7) + 8 * ((i >> 3) & 7);     // 8 heads per XCD
    const int q0 = (i >> 6) * 256;
    const int b = bh >> 4, h = bh & 15;

    const int lq = lane >> 4, lc = lane & 15;
    const int wm = w * 32;
    const int gl = (lane & 7) ^ ((lane >> 3) & 7);
    const int lc7 = lc & 7;

    // B-frag for the l-MFMA: column 0 = 1.0 (bf16), all other columns 0
    const short8 onesf = (short8)(lc == 0 ? (short)0x3F80 : (short)0);

    // ---- prologue A: count masked keys of batch b (l-correction scalar)
    {
        const int4 a = ((const int4*)(mask + b * SEQ))[t];
        int cnt = (a.x == 0) + (a.y == 0) + (a.z == 0) + (a.w == 0);
#pragma unroll
        for (int off = 1; off < 64; off <<= 1) cnt += __shfl_xor(cnt, off);
        if (lane == 0) ((float*)&smem[28672])[w] = (float)cnt;  // sV buf1: not staged yet
    }
    // ---- prologue B: stage Q tile (256 rows x 64 d) into sQ (= sP region)
#pragma unroll
    for (int j = 0; j < 4; j++) {
        const int i2 = w * 4 + j;
        gload_lds16(Q + ((size_t)bh * SEQ + q0 + i2 * 8 + (lane >> 3)) * 64 + gl * 8,
                    &smem[i2 * 512]);
    }
    // ---- prologue C: stage K(0), V(0) into buf0 (2 loads per wave)
    const ushort_t* gsrc;
    int gstride, jstride, dstb;
    if (w < 4) {
        gsrc = K + ((size_t)bh * SEQ + w * 16 + (lane >> 3)) * 64 + gl * 8;
        gstride = 64 * 64;  jstride = 8 * 64;   dstb = 16384 + w * 1024;
    } else {
        gsrc = Vt + ((size_t)bh * 64 + (w - 4) * 16 + (lane >> 3)) * SEQ + gl * 8;
        gstride = 64;       jstride = 8 * SEQ;  dstb = 24576 + (w - 4) * 1024;
    }
    gload_lds16(gsrc,           &smem[dstb]);
    gload_lds16(gsrc + jstride, &smem[dstb + 512]);
    gsrc += gstride;

    __syncthreads();   // drains vmcnt(0): Q + K0/V0 landed; cnt visible

    const float* cs = (const float*)&smem[28672];
    const float nmaskf = cs[0] + cs[1] + cs[2] + cs[3] +
                         cs[4] + cs[5] + cs[6] + cs[7];

    short8 aq[2][2];  // Q B-frags resident in regs; sQ region is dead after this
#pragma unroll
    for (int mt = 0; mt < 2; mt++)
#pragma unroll
        for (int kk = 0; kk < 2; kk++) {
            const int r = wm + mt * 16 + lc;
            aq[mt][kk] = *(const short8*)&smem[r * 64 + (((kk * 4 + lq) ^ (r & 7)) * 8)];
        }

    // ---- hoisted per-lane LDS offsets (ushort units)
    int aK[2], aPw[4], aPr[2];
#pragma unroll
    for (int kk = 0; kk < 2; kk++) {
        aK[kk]  = lc * 64 + (((kk * 4 + lq) ^ lc7) * 8);
        aPr[kk] = wm * 64 + aK[kk];
    }
#pragma unroll
    for (int kt4 = 0; kt4 < 4; kt4++)
        aPw[kt4] = wm * 64 + lc * 64 + (((kt4 * 2 + (lq >> 1)) ^ lc7) * 8) + (lq & 1) * 4;

    float4v O[2][4];
    float4v lacc[2];
#pragma unroll
    for (int mt = 0; mt < 2; mt++) {
#pragma unroll
        for (int nt = 0; nt < 4; nt++) O[mt][nt] = (float4v)(0.0f);
        lacc[mt] = (float4v)(0.0f);
    }

    __syncthreads();   // all waves' aq/nmask LDS reads done (sQ may be overwritten)

    for (int kt = 0; kt < 32; kt++) {
        const int cur = (kt & 1) * 4096;
        const int nxt = cur ^ 4096;

        // ---- issue next tile's staging FIRST (hides under this iter's MFMA)
        if (kt < 31) {
            gload_lds16(gsrc,           &smem[dstb + nxt]);
            gload_lds16(gsrc + jstride, &smem[dstb + nxt + 512]);
            gsrc += gstride;
        }

        // ---- S^T = K Q^T per kt4 (mask already folded into K); softmax fused
#pragma unroll
        for (int kt4 = 0; kt4 < 4; kt4++) {
            float4v s0 = (float4v)(0.0f), s1 = (float4v)(0.0f);
#pragma unroll
            for (int kk = 0; kk < 2; kk++) {
                short8 ak = *(const short8*)&smem[16384 + cur + kt4 * 1024 + aK[kk]];
                s0 = __builtin_amdgcn_mfma_f32_16x16x32_bf16(ak, aq[0][kk], s0, 0, 0, 0);
                s1 = __builtin_amdgcn_mfma_f32_16x16x32_bf16(ak, aq[1][kk], s1, 0, 0, 0);
            }
            // p = exp2(s), RNE-pack to bf16 pairs, store to sP (wave-private)
            {
                const float p0 = __builtin_amdgcn_exp2f(s0[0]);
                const float p1 = __builtin_amdgcn_exp2f(s0[1]);
                const float p2 = __builtin_amdgcn_exp2f(s0[2]);
                const float p3 = __builtin_amdgcn_exp2f(s0[3]);
                __hip_bfloat162 pk01 = __float22bfloat162_rn(make_float2(p0, p1));
                __hip_bfloat162 pk23 = __float22bfloat162_rn(make_float2(p2, p3));
                *(uint2*)&smem[aPw[kt4]] =
                    make_uint2(*(const uint_t*)&pk01, *(const uint_t*)&pk23);
            }
            {
                const float p0 = __builtin_amdgcn_exp2f(s1[0]);
                const float p1 = __builtin_amdgcn_exp2f(s1[1]);
                const float p2 = __builtin_amdgcn_exp2f(s1[2]);
                const float p3 = __builtin_amdgcn_exp2f(s1[3]);
                __hip_bfloat162 pk01 = __float22bfloat162_rn(make_float2(p0, p1));
                __hip_bfloat162 pk23 = __float22bfloat162_rn(make_float2(p2, p3));
                *(uint2*)&smem[1024 + aPw[kt4]] =
                    make_uint2(*(const uint_t*)&pk01, *(const uint_t*)&pk23);
            }
        }

        // ---- O += P @ V ; l += P @ ones-col (wave-private P rows; in-order LDS)
#pragma unroll
        for (int kk = 0; kk < 2; kk++) {
            short8 ap[2];
#pragma unroll
            for (int mt = 0; mt < 2; mt++)
                ap[mt] = *(const short8*)&smem[mt * 1024 + aPr[kk]];
            __builtin_amdgcn_s_setprio(1);
#pragma unroll
            for (int mt = 0; mt < 2; mt++)
                lacc[mt] = __builtin_amdgcn_mfma_f32_16x16x32_bf16(ap[mt], onesf, lacc[mt], 0, 0, 0);
#pragma unroll
            for (int nt = 0; nt < 4; nt++) {
                short8 bv = *(const short8*)&smem[24576 + cur + nt * 1024 + aK[kk]];
#pragma unroll
                for (int mt = 0; mt < 2; mt++)
                    O[mt][nt] = __builtin_amdgcn_mfma_f32_16x16x32_bf16(ap[mt], bv, O[mt][nt], 0, 0, 0);
            }
            __builtin_amdgcn_s_setprio(0);
        }

        // ---- own staging loads landed + all waves done reading [cur]
        asm volatile("s_waitcnt vmcnt(0)" ::: "memory");
        asm volatile("s_barrier" ::: "memory");
    }

    // ---- epilogue: l(col 0 of C-layout) minus exact masked count; normalize
#pragma unroll
    for (int mt = 0; mt < 2; mt++) {
#pragma unroll
        for (int r = 0; r < 4; r++) {
            const float lsum = __shfl(lacc[mt][r], lane & 48) - nmaskf;
            const float inv = 1.0f / lsum;
            const int srow = q0 + wm + mt * 16 + lq * 4 + r;
#pragma unroll
            for (int nt = 0; nt < 4; nt++) {
                const float v = O[mt][nt][r] * inv;
                const ushort_t hh = f2bf(v);
                const size_t idx = ((size_t)(b * SEQ + srow)) * 1024 + h * 64 + nt * 16 + lc;
                Oh[idx] = hh;
                Ol[idx] = f2bf(v - bf2f(hh));
            }
        }
    }
}

extern "C" void kernel_launch(void* const* d_in, const int* in_sizes, int n_in,
                              void* d_out, int out_size, void* d_ws, size_t ws_size,
                              hipStream_t stream) {
    const float* x    = (const float*)d_in[0];
    const int*   mask = (const int*)d_in[1];
    const float* Wq   = (const float*)d_in[2];
    const float* bq   = (const float*)d_in[3];
    const float* Wk   = (const float*)d_in[4];
    const float* bk   = (const float*)d_in[5];
    const float* Wv   = (const float*)d_in[6];
    const float* bv   = (const float*)d_in[7];
    const float* Wo   = (const float*)d_in[8];
    const float* bo   = (const float*)d_in[9];
    float* out = (float*)d_out;

    ushort_t* p = (ushort_t*)d_ws;
    const size_t PLANE  = (size_t)MROWS * DM;
    const size_t WPLANE = (size_t)DM * DM;
    ushort_t* xh  = p;  p += PLANE;
    ushort_t* wf  = p;  p += 3 * WPLANE;   // fused [Wq|Wk|Wv]^T
    ushort_t* woh = p;  p += WPLANE;
    ushort_t* wol = p;  p += WPLANE;
    ushort_t* Qh  = p;  p += PLANE;
    ushort_t* Kh  = p;  p += PLANE;
    ushort_t* Vth = p;  p += PLANE;
    ushort_t* Ath = p;  p += PLANE;
    ushort_t* Atl = p;  p += PLANE;

    dim3 blk(256);
    hipLaunchKernelGGL(prep, dim3(3072), blk, 0, stream,
                       x, xh, Wq, Wk, Wv, Wo, wf, woh, wol);
    hipLaunchKernelGGL(gemm_qkv, dim3(12, 64), dim3(512), 0, stream,
                       xh, wf, bq, bk, bv, mask, Qh, Kh, Vth);
    hipLaunchKernelGGL(flash_mfma, dim3(8, 64), dim3(512), 0, stream,
                       Qh, Kh, Vth, mask, Ath, Atl);
    hipLaunchKernelGGL(gemm_split3, dim3(4, 64), dim3(512), 0, stream,
                       Ath, Atl, woh, wol, bo, out);
}